// Round 4
// baseline (173509.399 us; speedup 1.0000x reference)
//
#include <hip/hip_runtime.h>

#define DD 1024        // hidden size
#define TT 8192        // sequence length
#define NBLK 256       // grid blocks == barrier participants (1 per CU)
#define NTHR 256       // 4 waves per block
#define RPB 4          // rows per block (one per wave)
#define FSP 128        // flag spacing in uints (512 B apart)

__device__ __forceinline__ float fast_sigmoid(float x) {
  x = fminf(fmaxf(x, -30.0f), 30.0f);
  return 1.0f / (1.0f + __expf(-x));
}

__device__ __forceinline__ float fast_tanh(float x) {
  x = fminf(fmaxf(x, -15.0f), 15.0f);
  float e = __expf(2.0f * x);
  return (e - 1.0f) / (e + 1.0f);
}

// Persistent LSTM. h-part weights (the post-barrier critical reads) live in
// 64KB LDS per block — the compiler cannot demote LDS (rounds 1/2 proved VGPR
// weight residency fails: VGPR_Count=100 => 33.5MB/step L2 restream).
// Sync: one flag per block; thread i polls block i's flag; release/acquire
// AGENT scope (validated rounds 1-2).
// BUGFIX vs round 3: biases are added ONCE after the 64-lane reduction —
// round 3 initialized accumulators with biases, so the butterfly summed the
// bias 64x (deterministic divergence, absmax 1.54).
__global__ __launch_bounds__(NTHR, 1) void lstm_seq(
    const float* __restrict__ X,      // [T, D]
    const float* __restrict__ enc_h,  // [D]
    const float* __restrict__ enc_c,  // [D]
    const float* __restrict__ Wf, const float* __restrict__ bf_,
    const float* __restrict__ Wi, const float* __restrict__ bi_,
    const float* __restrict__ Wc, const float* __restrict__ bc_,
    const float* __restrict__ Wo, const float* __restrict__ bo_,
    float* __restrict__ out,          // [T, D] h_t rows
    float* __restrict__ cbuf,         // [2][D] ring
    unsigned* __restrict__ flags)     // [NBLK * FSP]
{
  extern __shared__ float lds[];      // [RPB][4 gates][1024] h-part weights
  const int wv   = threadIdx.x >> 6;  // wave = local row 0..3
  const int lane = threadIdx.x & 63;
  const int j    = blockIdx.x * RPB + wv;

  // ---- stage h-part weights into LDS (once); gate order f,i,o,C ----
  for (int idx = threadIdx.x; idx < RPB * 4 * 256; idx += NTHR) {
    const int r = idx >> 10, g = (idx >> 8) & 3, q = idx & 255;
    const int row = blockIdx.x * RPB + r;
    const float* ws = (g == 0) ? Wf : (g == 1) ? Wi : (g == 2) ? Wo : Wc;
    *(float4*)&lds[idx * 4] = *(const float4*)(ws + (size_t)row * 2048 + q * 4);
  }

  // ---- per-lane constant weights in registers (x-parts + c-part) ----
  float wxf[16], wxi[16], wxo[16], wcc[16];
#pragma unroll
  for (int kb = 0; kb < 4; ++kb) {
    const int k = 1024 + kb * 256 + lane * 4;
    *(float4*)&wxf[kb*4] = *(const float4*)(Wf + (size_t)j * 2048 + k);
    *(float4*)&wxi[kb*4] = *(const float4*)(Wi + (size_t)j * 2048 + k);
    *(float4*)&wxo[kb*4] = *(const float4*)(Wo + (size_t)j * 2048 + k);
    *(float4*)&wcc[kb*4] = *(const float4*)(Wc + (size_t)j * 2048 + k);
  }
  const float Bf = bf_[j], Bi = bi_[j], Bc = bc_[j], Bo = bo_[j];
  const float* lw = lds + wv * 4096;  // this wave's [4][1024] h-weights

  __syncthreads();

  // x_0 preload; thereafter x_{t+1} is prefetched a full step ahead
  float4 xc0, xc1, xc2, xc3;
  {
    const float* xq = X + lane * 4;
    xc0 = *(const float4*)(xq);       xc1 = *(const float4*)(xq + 256);
    xc2 = *(const float4*)(xq + 512); xc3 = *(const float4*)(xq + 768);
  }

  for (int t = 0; t < TT; ++t) {
    // issue next-step x loads (HBM latency hides under this whole step)
    float4 xn0, xn1, xn2, xn3;
    {
      const size_t tn = (t + 1 < TT) ? (size_t)(t + 1) : (size_t)t;
      const float* xq = X + tn * DD + lane * 4;
      xn0 = *(const float4*)(xq);       xn1 = *(const float4*)(xq + 256);
      xn2 = *(const float4*)(xq + 512); xn3 = *(const float4*)(xq + 768);
    }

    // x-part MACs (barrier-independent). NO biases here — they'd be
    // multiplied 64x by the butterfly reduce (round-3 bug).
    float aF = 0.0f, aI = 0.0f, aO = 0.0f, aC = 0.0f;
#pragma unroll
    for (int kb = 0; kb < 4; ++kb) {
      const float4 xv = (kb==0)?xc0:(kb==1)?xc1:(kb==2)?xc2:xc3;
      const int b = kb * 4;
      aF += wxf[b]*xv.x + wxf[b+1]*xv.y + wxf[b+2]*xv.z + wxf[b+3]*xv.w;
      aI += wxi[b]*xv.x + wxi[b+1]*xv.y + wxi[b+2]*xv.z + wxi[b+3]*xv.w;
      aO += wxo[b]*xv.x + wxo[b+1]*xv.y + wxo[b+2]*xv.z + wxo[b+3]*xv.w;
    }

    if (t > 0) {
      // NTHR == NBLK: thread i polls block i's flag
      while (__hip_atomic_load(&flags[threadIdx.x * FSP], __ATOMIC_ACQUIRE,
                               __HIP_MEMORY_SCOPE_AGENT) < (unsigned)t) {
        __builtin_amdgcn_s_sleep(1);
      }
      __syncthreads();
    }

    const float* h  = (t == 0) ? enc_h : out  + (size_t)(t - 1) * DD;
    const float* cv = (t == 0) ? enc_c : cbuf + (size_t)((t - 1) & 1) * DD;

    const float cj = cv[j];
    const float* hp = h  + lane * 4;
    const float* cp = cv + lane * 4;
    float4 hv0 = *(const float4*)(hp);       float4 hv1 = *(const float4*)(hp + 256);
    float4 hv2 = *(const float4*)(hp + 512); float4 hv3 = *(const float4*)(hp + 768);
    float4 cv0 = *(const float4*)(cp);       float4 cv1 = *(const float4*)(cp + 256);
    float4 cv2 = *(const float4*)(cp + 512); float4 cv3 = *(const float4*)(cp + 768);

#pragma unroll
    for (int kb = 0; kb < 4; ++kb) {
      const int o = kb * 256 + lane * 4;
      const float4 hv = (kb==0)?hv0:(kb==1)?hv1:(kb==2)?hv2:hv3;
      const float4 cc = (kb==0)?cv0:(kb==1)?cv1:(kb==2)?cv2:cv3;
      const float4 wF = *(const float4*)&lw[o];
      const float4 wI = *(const float4*)&lw[1024 + o];
      const float4 wO = *(const float4*)&lw[2048 + o];
      const float4 wC = *(const float4*)&lw[3072 + o];
      const int b = kb * 4;
      aF += wF.x*hv.x + wF.y*hv.y + wF.z*hv.z + wF.w*hv.w;
      aI += wI.x*hv.x + wI.y*hv.y + wI.z*hv.z + wI.w*hv.w;
      aO += wO.x*hv.x + wO.y*hv.y + wO.z*hv.z + wO.w*hv.w;
      aC += wC.x*hv.x + wC.y*hv.y + wC.z*hv.z + wC.w*hv.w;
      aC += wcc[b]*cc.x + wcc[b+1]*cc.y + wcc[b+2]*cc.z + wcc[b+3]*cc.w;
    }

#pragma unroll
    for (int m = 32; m >= 1; m >>= 1) {
      aF += __shfl_xor(aF, m, 64);
      aI += __shfl_xor(aI, m, 64);
      aO += __shfl_xor(aO, m, 64);
      aC += __shfl_xor(aC, m, 64);
    }

    // biases added exactly once, post-reduction
    const float fg = fast_sigmoid(aF + Bf);
    const float ig = fast_sigmoid(aI + Bi);
    const float og = fast_sigmoid(aO + Bo);
    const float ct = fast_tanh(aC + Bc);
    const float cn = fg * cj + ig * ct;
    const float hn = og * fast_tanh(cn);

    if (lane == 0) {
      out[(size_t)t * DD + j]        = hn;
      cbuf[(size_t)(t & 1) * DD + j] = cn;
    }
    __syncthreads();  // drains vmcnt: all rows' stores are in L2
    if (threadIdx.x == 0) {
      __hip_atomic_store(&flags[blockIdx.x * FSP], (unsigned)(t + 1),
                         __ATOMIC_RELEASE, __HIP_MEMORY_SCOPE_AGENT);
    }
    xc0 = xn0; xc1 = xn1; xc2 = xn2; xc3 = xn3;
  }
}

extern "C" void kernel_launch(void* const* d_in, const int* in_sizes, int n_in,
                              void* d_out, int out_size, void* d_ws, size_t ws_size,
                              hipStream_t stream) {
  const float* X    = (const float*)d_in[0];
  const float* eh   = (const float*)d_in[1];
  const float* ec   = (const float*)d_in[2];
  const float* Wf   = (const float*)d_in[3];
  const float* bf_  = (const float*)d_in[4];
  const float* Wi   = (const float*)d_in[5];
  const float* bi_  = (const float*)d_in[6];
  const float* Wc   = (const float*)d_in[7];
  const float* bc_  = (const float*)d_in[8];
  const float* Wo   = (const float*)d_in[9];
  const float* bo_  = (const float*)d_in[10];
  float* out = (float*)d_out;

  const size_t flagsz = (size_t)NBLK * FSP * sizeof(unsigned);  // 128 KB
  unsigned* flags = (unsigned*)d_ws;
  float* cbuf = (float*)((char*)d_ws + flagsz);                 // 8 KB

  hipMemsetAsync(d_ws, 0, flagsz, stream);

  void* args[] = {(void*)&X, (void*)&eh, (void*)&ec,
                  (void*)&Wf, (void*)&bf_, (void*)&Wi, (void*)&bi_,
                  (void*)&Wc, (void*)&bc_, (void*)&Wo, (void*)&bo_,
                  (void*)&out, (void*)&cbuf, (void*)&flags};
  hipError_t e = hipLaunchCooperativeKernel((const void*)lstm_seq,
                                            dim3(NBLK), dim3(NTHR),
                                            args, 65536, stream);
  if (e != hipSuccess) {
    // plain-launch fallback: 256 blocks x 64KB LDS => co-resident (1-2/CU)
    lstm_seq<<<dim3(NBLK), dim3(NTHR), 65536, stream>>>(
        X, eh, ec, Wf, bf_, Wi, bi_, Wc, bc_, Wo, bo_, out, cbuf, flags);
  }
}

// Round 5
// 98846.436 us; speedup vs baseline: 1.7553x; 1.7553x over previous
//
#include <hip/hip_runtime.h>

#define DD 1024        // hidden size
#define TT 8192        // sequence length
#define NBLK 256       // grid blocks == barrier participants (1 per CU)
#define NTHR 256       // 4 waves per block
#define RPB 4          // rows per block (one per wave)

__device__ __forceinline__ float fast_sigmoid(float x) {
  x = fminf(fmaxf(x, -30.0f), 30.0f);
  return 1.0f / (1.0f + __expf(-x));
}

__device__ __forceinline__ float fast_tanh(float x) {
  x = fminf(fmaxf(x, -15.0f), 15.0f);
  float e = __expf(2.0f * x);
  return (e - 1.0f) / (e + 1.0f);
}

// Persistent LSTM, h-part weights in 64KB LDS (R4-validated compute core).
// Barrier redesign vs R4 (whose 65536 acquire-pollers on 256 spread lines
// congested the coherence fabric, 21us/step): flags PACKED 4B apart (16
// lines total); ONLY wave 0 of each block polls, 4 coalesced relaxed loads
// per lane per round + ONE wave-level acquire fence per round. Poll fetch
// traffic drops ~256x; release/acquire pairing preserved (fence-in-loop
// keeps the refresh + final acquire orders the h/c reads).
__global__ __launch_bounds__(NTHR, 1) void lstm_seq(
    const float* __restrict__ X,      // [T, D]
    const float* __restrict__ enc_h,  // [D]
    const float* __restrict__ enc_c,  // [D]
    const float* __restrict__ Wf, const float* __restrict__ bf_,
    const float* __restrict__ Wi, const float* __restrict__ bi_,
    const float* __restrict__ Wc, const float* __restrict__ bc_,
    const float* __restrict__ Wo, const float* __restrict__ bo_,
    float* __restrict__ out,          // [T, D] h_t rows
    float* __restrict__ cbuf,         // [2][D] ring
    unsigned* __restrict__ flags)     // [NBLK] packed
{
  extern __shared__ float lds[];      // [RPB][4 gates][1024] h-part weights
  const int wv   = threadIdx.x >> 6;  // wave = local row 0..3
  const int lane = threadIdx.x & 63;
  const int j    = blockIdx.x * RPB + wv;

  // ---- stage h-part weights into LDS (once); gate order f,i,o,C ----
  for (int idx = threadIdx.x; idx < RPB * 4 * 256; idx += NTHR) {
    const int r = idx >> 10, g = (idx >> 8) & 3, q = idx & 255;
    const int row = blockIdx.x * RPB + r;
    const float* ws = (g == 0) ? Wf : (g == 1) ? Wi : (g == 2) ? Wo : Wc;
    *(float4*)&lds[idx * 4] = *(const float4*)(ws + (size_t)row * 2048 + q * 4);
  }

  // ---- per-lane constant weights in registers (x-parts + c-part) ----
  float wxf[16], wxi[16], wxo[16], wcc[16];
#pragma unroll
  for (int kb = 0; kb < 4; ++kb) {
    const int k = 1024 + kb * 256 + lane * 4;
    *(float4*)&wxf[kb*4] = *(const float4*)(Wf + (size_t)j * 2048 + k);
    *(float4*)&wxi[kb*4] = *(const float4*)(Wi + (size_t)j * 2048 + k);
    *(float4*)&wxo[kb*4] = *(const float4*)(Wo + (size_t)j * 2048 + k);
    *(float4*)&wcc[kb*4] = *(const float4*)(Wc + (size_t)j * 2048 + k);
  }
  const float Bf = bf_[j], Bi = bi_[j], Bc = bc_[j], Bo = bo_[j];
  const float* lw = lds + wv * 4096;  // this wave's [4][1024] h-weights

  __syncthreads();

  // x_0 preload; thereafter x_{t+1} is prefetched a full step ahead
  float4 xc0, xc1, xc2, xc3;
  {
    const float* xq = X + lane * 4;
    xc0 = *(const float4*)(xq);       xc1 = *(const float4*)(xq + 256);
    xc2 = *(const float4*)(xq + 512); xc3 = *(const float4*)(xq + 768);
  }

  for (int t = 0; t < TT; ++t) {
    // issue next-step x loads (HBM latency hides under this whole step)
    float4 xn0, xn1, xn2, xn3;
    {
      const size_t tn = (t + 1 < TT) ? (size_t)(t + 1) : (size_t)t;
      const float* xq = X + tn * DD + lane * 4;
      xn0 = *(const float4*)(xq);       xn1 = *(const float4*)(xq + 256);
      xn2 = *(const float4*)(xq + 512); xn3 = *(const float4*)(xq + 768);
    }

    // x-part MACs (barrier-independent; biases added post-reduce)
    float aF = 0.0f, aI = 0.0f, aO = 0.0f, aC = 0.0f;
#pragma unroll
    for (int kb = 0; kb < 4; ++kb) {
      const float4 xv = (kb==0)?xc0:(kb==1)?xc1:(kb==2)?xc2:xc3;
      const int b = kb * 4;
      aF += wxf[b]*xv.x + wxf[b+1]*xv.y + wxf[b+2]*xv.z + wxf[b+3]*xv.w;
      aI += wxi[b]*xv.x + wxi[b+1]*xv.y + wxi[b+2]*xv.z + wxi[b+3]*xv.w;
      aO += wxo[b]*xv.x + wxo[b+1]*xv.y + wxo[b+2]*xv.z + wxo[b+3]*xv.w;
    }

    if (t > 0) {
      if (threadIdx.x < 64) {  // wave 0 only: coalesced poll of all 256 flags
        const unsigned tt = (unsigned)t;
        for (;;) {
          unsigned a = __hip_atomic_load(&flags[lane      ], __ATOMIC_RELAXED, __HIP_MEMORY_SCOPE_AGENT);
          unsigned b = __hip_atomic_load(&flags[lane +  64], __ATOMIC_RELAXED, __HIP_MEMORY_SCOPE_AGENT);
          unsigned c = __hip_atomic_load(&flags[lane + 128], __ATOMIC_RELAXED, __HIP_MEMORY_SCOPE_AGENT);
          unsigned d = __hip_atomic_load(&flags[lane + 192], __ATOMIC_RELAXED, __HIP_MEMORY_SCOPE_AGENT);
          bool ok = (a >= tt) & (b >= tt) & (c >= tt) & (d >= tt);
          if (__all(ok)) break;
          // refresh caches so relaxed re-loads can't spin on stale lines;
          // one wave-level fence per round (vs per-thread-per-load in R4)
          __builtin_amdgcn_fence(__ATOMIC_ACQUIRE, "agent");
          __builtin_amdgcn_s_sleep(1);
        }
        __builtin_amdgcn_fence(__ATOMIC_ACQUIRE, "agent");  // order h/c reads
      }
      __syncthreads();
    }

    const float* h  = (t == 0) ? enc_h : out  + (size_t)(t - 1) * DD;
    const float* cv = (t == 0) ? enc_c : cbuf + (size_t)((t - 1) & 1) * DD;

    const float cj = cv[j];
    const float* hp = h  + lane * 4;
    const float* cp = cv + lane * 4;
    float4 hv0 = *(const float4*)(hp);       float4 hv1 = *(const float4*)(hp + 256);
    float4 hv2 = *(const float4*)(hp + 512); float4 hv3 = *(const float4*)(hp + 768);
    float4 cv0 = *(const float4*)(cp);       float4 cv1 = *(const float4*)(cp + 256);
    float4 cv2 = *(const float4*)(cp + 512); float4 cv3 = *(const float4*)(cp + 768);

#pragma unroll
    for (int kb = 0; kb < 4; ++kb) {
      const int o = kb * 256 + lane * 4;
      const float4 hv = (kb==0)?hv0:(kb==1)?hv1:(kb==2)?hv2:hv3;
      const float4 cc = (kb==0)?cv0:(kb==1)?cv1:(kb==2)?cv2:cv3;
      const float4 wF = *(const float4*)&lw[o];
      const float4 wI = *(const float4*)&lw[1024 + o];
      const float4 wO = *(const float4*)&lw[2048 + o];
      const float4 wC = *(const float4*)&lw[3072 + o];
      const int b = kb * 4;
      aF += wF.x*hv.x + wF.y*hv.y + wF.z*hv.z + wF.w*hv.w;
      aI += wI.x*hv.x + wI.y*hv.y + wI.z*hv.z + wI.w*hv.w;
      aO += wO.x*hv.x + wO.y*hv.y + wO.z*hv.z + wO.w*hv.w;
      aC += wC.x*hv.x + wC.y*hv.y + wC.z*hv.z + wC.w*hv.w;
      aC += wcc[b]*cc.x + wcc[b+1]*cc.y + wcc[b+2]*cc.z + wcc[b+3]*cc.w;
    }

#pragma unroll
    for (int m = 32; m >= 1; m >>= 1) {
      aF += __shfl_xor(aF, m, 64);
      aI += __shfl_xor(aI, m, 64);
      aO += __shfl_xor(aO, m, 64);
      aC += __shfl_xor(aC, m, 64);
    }

    // biases added exactly once, post-reduction (round-3 lesson)
    const float fg = fast_sigmoid(aF + Bf);
    const float ig = fast_sigmoid(aI + Bi);
    const float og = fast_sigmoid(aO + Bo);
    const float ct = fast_tanh(aC + Bc);
    const float cn = fg * cj + ig * ct;
    const float hn = og * fast_tanh(cn);

    if (lane == 0) {
      out[(size_t)t * DD + j]        = hn;
      cbuf[(size_t)(t & 1) * DD + j] = cn;
    }
    __syncthreads();  // drains vmcnt: all rows' stores are in L2
    if (threadIdx.x == 0) {
      __hip_atomic_store(&flags[blockIdx.x], (unsigned)(t + 1),
                         __ATOMIC_RELEASE, __HIP_MEMORY_SCOPE_AGENT);
    }
    xc0 = xn0; xc1 = xn1; xc2 = xn2; xc3 = xn3;
  }
}

extern "C" void kernel_launch(void* const* d_in, const int* in_sizes, int n_in,
                              void* d_out, int out_size, void* d_ws, size_t ws_size,
                              hipStream_t stream) {
  const float* X    = (const float*)d_in[0];
  const float* eh   = (const float*)d_in[1];
  const float* ec   = (const float*)d_in[2];
  const float* Wf   = (const float*)d_in[3];
  const float* bf_  = (const float*)d_in[4];
  const float* Wi   = (const float*)d_in[5];
  const float* bi_  = (const float*)d_in[6];
  const float* Wc   = (const float*)d_in[7];
  const float* bc_  = (const float*)d_in[8];
  const float* Wo   = (const float*)d_in[9];
  const float* bo_  = (const float*)d_in[10];
  float* out = (float*)d_out;

  unsigned* flags = (unsigned*)d_ws;                 // 256 u32, packed (1 KB)
  float* cbuf = (float*)((char*)d_ws + 1024);        // [2][1024] ring (8 KB)

  hipMemsetAsync(d_ws, 0, 1024, stream);

  void* args[] = {(void*)&X, (void*)&eh, (void*)&ec,
                  (void*)&Wf, (void*)&bf_, (void*)&Wi, (void*)&bi_,
                  (void*)&Wc, (void*)&bc_, (void*)&Wo, (void*)&bo_,
                  (void*)&out, (void*)&cbuf, (void*)&flags};
  hipError_t e = hipLaunchCooperativeKernel((const void*)lstm_seq,
                                            dim3(NBLK), dim3(NTHR),
                                            args, 65536, stream);
  if (e != hipSuccess) {
    // plain-launch fallback: 256 blocks x 64KB LDS => co-resident (1-2/CU)
    lstm_seq<<<dim3(NBLK), dim3(NTHR), 65536, stream>>>(
        X, eh, ec, Wf, bf_, Wi, bi_, Wc, bc_, Wo, bo_, out, cbuf, flags);
  }
}

// Round 6
// 60165.625 us; speedup vs baseline: 2.8839x; 1.6429x over previous
//
#include <hip/hip_runtime.h>

#define DD 1024        // hidden size
#define TT 8192        // sequence length
#define NBLK 128       // grid blocks == barrier participants
#define NTHR 512       // 8 waves per block
#define RPB 8          // rows per block (one per wave)
#define LDSB (RPB * 4 * DD * 4)  // 128 KB: h-part weights, 4 gates x 8 rows

__device__ __forceinline__ float fast_sigmoid(float x) {
  x = fminf(fmaxf(x, -30.0f), 30.0f);
  return 1.0f / (1.0f + __expf(-x));
}

__device__ __forceinline__ float fast_tanh(float x) {
  x = fminf(fmaxf(x, -15.0f), 15.0f);
  float e = __expf(2.0f * x);
  return (e - 1.0f) / (e + 1.0f);
}

// Persistent LSTM. h-part weights in 128KB LDS (compiler can't demote; fp32).
// Sync fabric (R5 lesson): poll with RELAXED agent atomic loads ONLY — atomic
// loads reach the coherence point by construction, no fence needed for
// progress. Exactly ONE acquire fence after the loop orders the h/c reads.
// 128 participants (vs R5's 256) halves fan-in/tail; 8 waves/CU hides latency.
__global__ __launch_bounds__(NTHR, 2) void lstm_seq(
    const float* __restrict__ X,      // [T, D]
    const float* __restrict__ enc_h,  // [D]
    const float* __restrict__ enc_c,  // [D]
    const float* __restrict__ Wf, const float* __restrict__ bf_,
    const float* __restrict__ Wi, const float* __restrict__ bi_,
    const float* __restrict__ Wc, const float* __restrict__ bc_,
    const float* __restrict__ Wo, const float* __restrict__ bo_,
    float* __restrict__ out,          // [T, D] h_t rows
    float* __restrict__ cbuf,         // [2][D] ring
    unsigned* __restrict__ flags)     // [NBLK] packed (512 B)
{
  extern __shared__ float lds[];      // [RPB][4 gates][1024]
  const int wv   = threadIdx.x >> 6;  // wave = local row 0..7
  const int lane = threadIdx.x & 63;
  const int j    = blockIdx.x * RPB + wv;

  // ---- stage h-part weights into LDS (once); gate order f,i,o,C ----
  for (int idx = threadIdx.x; idx < RPB * 4 * 256; idx += NTHR) {
    const int r = idx >> 10, g = (idx >> 8) & 3, q = idx & 255;
    const int row = blockIdx.x * RPB + r;
    const float* ws = (g == 0) ? Wf : (g == 1) ? Wi : (g == 2) ? Wo : Wc;
    *(float4*)&lds[idx * 4] = *(const float4*)(ws + (size_t)row * 2048 + q * 4);
  }

  // ---- per-lane constant weights in registers (x-parts + c-part) ----
  float wxf[16], wxi[16], wxo[16], wcc[16];
#pragma unroll
  for (int kb = 0; kb < 4; ++kb) {
    const int k = 1024 + kb * 256 + lane * 4;
    *(float4*)&wxf[kb*4] = *(const float4*)(Wf + (size_t)j * 2048 + k);
    *(float4*)&wxi[kb*4] = *(const float4*)(Wi + (size_t)j * 2048 + k);
    *(float4*)&wxo[kb*4] = *(const float4*)(Wo + (size_t)j * 2048 + k);
    *(float4*)&wcc[kb*4] = *(const float4*)(Wc + (size_t)j * 2048 + k);
  }
  const float Bf = bf_[j], Bi = bi_[j], Bc = bc_[j], Bo = bo_[j];
  const float* lw = lds + wv * 4096;  // this wave's [4][1024] h-weights

  // c_j carried in a register: this wave computes row j's c every step, so
  // the dependent remote scalar load is unnecessary after t=0.
  float cj = enc_c[j];

  __syncthreads();

  // x_0 preload; thereafter x_{t+1} is prefetched a full step ahead
  float4 xc0, xc1, xc2, xc3;
  {
    const float* xq = X + lane * 4;
    xc0 = *(const float4*)(xq);       xc1 = *(const float4*)(xq + 256);
    xc2 = *(const float4*)(xq + 512); xc3 = *(const float4*)(xq + 768);
  }

  for (int t = 0; t < TT; ++t) {
    // issue next-step x loads (HBM latency hides under this whole step)
    float4 xn0, xn1, xn2, xn3;
    {
      const size_t tn = (t + 1 < TT) ? (size_t)(t + 1) : (size_t)t;
      const float* xq = X + tn * DD + lane * 4;
      xn0 = *(const float4*)(xq);       xn1 = *(const float4*)(xq + 256);
      xn2 = *(const float4*)(xq + 512); xn3 = *(const float4*)(xq + 768);
    }

    // x-part MACs (barrier-independent; biases added post-reduce — R3 lesson)
    float aF = 0.0f, aI = 0.0f, aO = 0.0f, aC = 0.0f;
#pragma unroll
    for (int kb = 0; kb < 4; ++kb) {
      const float4 xv = (kb==0)?xc0:(kb==1)?xc1:(kb==2)?xc2:xc3;
      const int b = kb * 4;
      aF += wxf[b]*xv.x + wxf[b+1]*xv.y + wxf[b+2]*xv.z + wxf[b+3]*xv.w;
      aI += wxi[b]*xv.x + wxi[b+1]*xv.y + wxi[b+2]*xv.z + wxi[b+3]*xv.w;
      aO += wxo[b]*xv.x + wxo[b+1]*xv.y + wxo[b+2]*xv.z + wxo[b+3]*xv.w;
    }

    if (t > 0) {
      if (threadIdx.x < 64) {  // wave 0: coalesced poll, 2 loads/lane/round
        const unsigned tt = (unsigned)t;
        for (;;) {
          unsigned a = __hip_atomic_load(&flags[lane     ], __ATOMIC_RELAXED, __HIP_MEMORY_SCOPE_AGENT);
          unsigned b = __hip_atomic_load(&flags[lane + 64], __ATOMIC_RELAXED, __HIP_MEMORY_SCOPE_AGENT);
          if (__all((a >= tt) & (b >= tt))) break;
          __builtin_amdgcn_s_sleep(1);
        }
        // single acquire fence: order the h/c reads below (L1 refresh)
        __builtin_amdgcn_fence(__ATOMIC_ACQUIRE, "agent");
      }
      __syncthreads();
    }

    const float* h  = (t == 0) ? enc_h : out  + (size_t)(t - 1) * DD;
    const float* cv = (t == 0) ? enc_c : cbuf + (size_t)((t - 1) & 1) * DD;

    const float* hp = h  + lane * 4;
    const float* cp = cv + lane * 4;
    float4 hv0 = *(const float4*)(hp);       float4 hv1 = *(const float4*)(hp + 256);
    float4 hv2 = *(const float4*)(hp + 512); float4 hv3 = *(const float4*)(hp + 768);
    float4 cv0 = *(const float4*)(cp);       float4 cv1 = *(const float4*)(cp + 256);
    float4 cv2 = *(const float4*)(cp + 512); float4 cv3 = *(const float4*)(cp + 768);

#pragma unroll
    for (int kb = 0; kb < 4; ++kb) {
      const int o = kb * 256 + lane * 4;
      const float4 hv = (kb==0)?hv0:(kb==1)?hv1:(kb==2)?hv2:hv3;
      const float4 cc = (kb==0)?cv0:(kb==1)?cv1:(kb==2)?cv2:cv3;
      const float4 wF = *(const float4*)&lw[o];
      const float4 wI = *(const float4*)&lw[1024 + o];
      const float4 wO = *(const float4*)&lw[2048 + o];
      const float4 wC = *(const float4*)&lw[3072 + o];
      const int b = kb * 4;
      aF += wF.x*hv.x + wF.y*hv.y + wF.z*hv.z + wF.w*hv.w;
      aI += wI.x*hv.x + wI.y*hv.y + wI.z*hv.z + wI.w*hv.w;
      aO += wO.x*hv.x + wO.y*hv.y + wO.z*hv.z + wO.w*hv.w;
      aC += wC.x*hv.x + wC.y*hv.y + wC.z*hv.z + wC.w*hv.w;
      aC += wcc[b]*cc.x + wcc[b+1]*cc.y + wcc[b+2]*cc.z + wcc[b+3]*cc.w;
    }

#pragma unroll
    for (int m = 32; m >= 1; m >>= 1) {
      aF += __shfl_xor(aF, m, 64);
      aI += __shfl_xor(aI, m, 64);
      aO += __shfl_xor(aO, m, 64);
      aC += __shfl_xor(aC, m, 64);
    }

    // biases added exactly once, post-reduction
    const float fg = fast_sigmoid(aF + Bf);
    const float ig = fast_sigmoid(aI + Bi);
    const float og = fast_sigmoid(aO + Bo);
    const float ct = fast_tanh(aC + Bc);
    const float cn = fg * cj + ig * ct;
    const float hn = og * fast_tanh(cn);
    cj = cn;  // register carry for next step

    if (lane == 0) {
      out[(size_t)t * DD + j]        = hn;
      cbuf[(size_t)(t & 1) * DD + j] = cn;
    }
    __syncthreads();  // all 8 waves' stores issued (vmcnt drained per wave)
    if (threadIdx.x == 0) {
      // release: buffer_wbl2 flushes this XCD's dirty h/c lines to the
      // coherence point before the flag becomes visible
      __hip_atomic_store(&flags[blockIdx.x], (unsigned)(t + 1),
                         __ATOMIC_RELEASE, __HIP_MEMORY_SCOPE_AGENT);
    }
    xc0 = xn0; xc1 = xn1; xc2 = xn2; xc3 = xn3;
  }
}

extern "C" void kernel_launch(void* const* d_in, const int* in_sizes, int n_in,
                              void* d_out, int out_size, void* d_ws, size_t ws_size,
                              hipStream_t stream) {
  const float* X    = (const float*)d_in[0];
  const float* eh   = (const float*)d_in[1];
  const float* ec   = (const float*)d_in[2];
  const float* Wf   = (const float*)d_in[3];
  const float* bf_  = (const float*)d_in[4];
  const float* Wi   = (const float*)d_in[5];
  const float* bi_  = (const float*)d_in[6];
  const float* Wc   = (const float*)d_in[7];
  const float* bc_  = (const float*)d_in[8];
  const float* Wo   = (const float*)d_in[9];
  const float* bo_  = (const float*)d_in[10];
  float* out = (float*)d_out;

  unsigned* flags = (unsigned*)d_ws;                 // 128 u32 packed (512 B)
  float* cbuf = (float*)((char*)d_ws + 1024);        // [2][1024] ring (8 KB)

  hipMemsetAsync(d_ws, 0, 1024, stream);

  // allow 128 KB dynamic LDS (default cap is 64 KB)
  hipFuncSetAttribute((const void*)lstm_seq,
                      hipFuncAttributeMaxDynamicSharedMemorySize, LDSB);

  void* args[] = {(void*)&X, (void*)&eh, (void*)&ec,
                  (void*)&Wf, (void*)&bf_, (void*)&Wi, (void*)&bi_,
                  (void*)&Wc, (void*)&bc_, (void*)&Wo, (void*)&bo_,
                  (void*)&out, (void*)&cbuf, (void*)&flags};
  hipError_t e = hipLaunchCooperativeKernel((const void*)lstm_seq,
                                            dim3(NBLK), dim3(NTHR),
                                            args, LDSB, stream);
  if (e != hipSuccess) {
    // plain-launch fallback: 128 blocks x 128KB LDS => 1 block/CU, co-resident
    lstm_seq<<<dim3(NBLK), dim3(NTHR), LDSB, stream>>>(
        X, eh, ec, Wf, bf_, Wi, bi_, Wc, bc_, Wo, bo_, out, cbuf, flags);
  }
}

// Round 7
// 38513.412 us; speedup vs baseline: 4.5052x; 1.5622x over previous
//
#include <hip/hip_runtime.h>

#define DD 1024        // hidden size
#define TT 8192        // sequence length
#define NBLK 128       // grid blocks == barrier participants
#define NTHR 512       // 8 waves per block
#define RPB 8          // rows per block (one per wave)
#define LDSB (RPB * 4 * DD * 4)  // 128 KB: h-part weights, 4 gates x 8 rows

__device__ __forceinline__ float fast_sigmoid(float x) {
  x = fminf(fmaxf(x, -30.0f), 30.0f);
  return 1.0f / (1.0f + __expf(-x));
}

__device__ __forceinline__ float fast_tanh(float x) {
  x = fminf(fmaxf(x, -15.0f), 15.0f);
  float e = __expf(2.0f * x);
  return (e - 1.0f) / (e + 1.0f);
}

union HC { unsigned long long u; float2 f; };

// Persistent LSTM, h-part weights in 128KB LDS (validated core).
// R7 sync fabric: ZERO cache-maintenance per step.
//  - producer: {h,c} packed in one 8B word per row, relaxed AGENT atomic
//    store (write-through to the coherence point); flag release-store after
//    __syncthreads provides belt-and-suspenders ordering.
//  - consumer: poll flags with relaxed AGENT atomic loads (they read the
//    coherence point by construction), NO acquire fence (R6's buffer_inv
//    per step evicted all warm lines), then 16x 8B relaxed atomic loads
//    fetch h AND c together in one hop.
__global__ __launch_bounds__(NTHR, 2) void lstm_seq(
    const float* __restrict__ X,      // [T, D]
    const float* __restrict__ enc_h,  // [D]
    const float* __restrict__ enc_c,  // [D]
    const float* __restrict__ Wf, const float* __restrict__ bf_,
    const float* __restrict__ Wi, const float* __restrict__ bi_,
    const float* __restrict__ Wc, const float* __restrict__ bc_,
    const float* __restrict__ Wo, const float* __restrict__ bo_,
    float* __restrict__ out,          // [T, D] h_t rows
    unsigned long long* __restrict__ hcbuf,  // [2][D] ring of packed {h,c}
    unsigned* __restrict__ flags)     // [NBLK] packed (512 B)
{
  extern __shared__ float lds[];      // [RPB][4 gates][1024]
  const int wv   = threadIdx.x >> 6;  // wave = local row 0..7
  const int lane = threadIdx.x & 63;
  const int j    = blockIdx.x * RPB + wv;

  // ---- stage h-part weights into LDS (once); gate order f,i,o,C ----
  for (int idx = threadIdx.x; idx < RPB * 4 * 256; idx += NTHR) {
    const int r = idx >> 10, g = (idx >> 8) & 3, q = idx & 255;
    const int row = blockIdx.x * RPB + r;
    const float* ws = (g == 0) ? Wf : (g == 1) ? Wi : (g == 2) ? Wo : Wc;
    *(float4*)&lds[idx * 4] = *(const float4*)(ws + (size_t)row * 2048 + q * 4);
  }

  // ---- per-lane constant weights in registers (x-parts + c-part) ----
  float wxf[16], wxi[16], wxo[16], wcc[16];
#pragma unroll
  for (int kb = 0; kb < 4; ++kb) {
    const int k = 1024 + kb * 256 + lane * 4;
    *(float4*)&wxf[kb*4] = *(const float4*)(Wf + (size_t)j * 2048 + k);
    *(float4*)&wxi[kb*4] = *(const float4*)(Wi + (size_t)j * 2048 + k);
    *(float4*)&wxo[kb*4] = *(const float4*)(Wo + (size_t)j * 2048 + k);
    *(float4*)&wcc[kb*4] = *(const float4*)(Wc + (size_t)j * 2048 + k);
  }
  const float Bf = bf_[j], Bi = bi_[j], Bc = bc_[j], Bo = bo_[j];
  const float* lw = lds + wv * 4096;  // this wave's [4][1024] h-weights

  float cj = enc_c[j];  // register carry of this row's cell state

  __syncthreads();

  // x_0 preload; thereafter x_{t+1} is prefetched a full step ahead
  float4 xc0, xc1, xc2, xc3;
  {
    const float* xq = X + lane * 4;
    xc0 = *(const float4*)(xq);       xc1 = *(const float4*)(xq + 256);
    xc2 = *(const float4*)(xq + 512); xc3 = *(const float4*)(xq + 768);
  }

  for (int t = 0; t < TT; ++t) {
    // issue next-step x loads (HBM latency hides under this whole step)
    float4 xn0, xn1, xn2, xn3;
    {
      const size_t tn = (t + 1 < TT) ? (size_t)(t + 1) : (size_t)t;
      const float* xq = X + tn * DD + lane * 4;
      xn0 = *(const float4*)(xq);       xn1 = *(const float4*)(xq + 256);
      xn2 = *(const float4*)(xq + 512); xn3 = *(const float4*)(xq + 768);
    }

    // x-part MACs (barrier-independent; biases added post-reduce — R3 lesson)
    float aF = 0.0f, aI = 0.0f, aO = 0.0f, aC = 0.0f;
#pragma unroll
    for (int kb = 0; kb < 4; ++kb) {
      const float4 xv = (kb==0)?xc0:(kb==1)?xc1:(kb==2)?xc2:xc3;
      const int b = kb * 4;
      aF += wxf[b]*xv.x + wxf[b+1]*xv.y + wxf[b+2]*xv.z + wxf[b+3]*xv.w;
      aI += wxi[b]*xv.x + wxi[b+1]*xv.y + wxi[b+2]*xv.z + wxi[b+3]*xv.w;
      aO += wxo[b]*xv.x + wxo[b+1]*xv.y + wxo[b+2]*xv.z + wxo[b+3]*xv.w;
    }

    if (t > 0) {
      if (threadIdx.x < 64) {  // wave 0: coalesced poll, 2 loads/lane/round
        const unsigned tt = (unsigned)t;
        for (;;) {
          unsigned a = __hip_atomic_load(&flags[lane     ], __ATOMIC_RELAXED, __HIP_MEMORY_SCOPE_AGENT);
          unsigned b = __hip_atomic_load(&flags[lane + 64], __ATOMIC_RELAXED, __HIP_MEMORY_SCOPE_AGENT);
          if (__all((a >= tt) & (b >= tt))) break;
        }
        // no fence: data is read via coherence-point atomics below
      }
      __syncthreads();
    }

    if (t == 0) {
      // initial state from inputs (plain loads; no dependency yet)
      const float* hp = enc_h + lane * 4;
      const float* cp = enc_c + lane * 4;
#pragma unroll
      for (int kb = 0; kb < 4; ++kb) {
        const int o = kb * 256 + lane * 4;
        const float4 hv = *(const float4*)(hp + kb * 256);
        const float4 cc = *(const float4*)(cp + kb * 256);
        const float4 wF = *(const float4*)&lw[o];
        const float4 wI = *(const float4*)&lw[1024 + o];
        const float4 wO = *(const float4*)&lw[2048 + o];
        const float4 wC = *(const float4*)&lw[3072 + o];
        const int b = kb * 4;
        aF += wF.x*hv.x + wF.y*hv.y + wF.z*hv.z + wF.w*hv.w;
        aI += wI.x*hv.x + wI.y*hv.y + wI.z*hv.z + wI.w*hv.w;
        aO += wO.x*hv.x + wO.y*hv.y + wO.z*hv.z + wO.w*hv.w;
        aC += wC.x*hv.x + wC.y*hv.y + wC.z*hv.z + wC.w*hv.w;
        aC += wcc[b]*cc.x + wcc[b+1]*cc.y + wcc[b+2]*cc.z + wcc[b+3]*cc.w;
      }
    } else {
      // fetch {h,c} pairs in one hop: 16x 8B coherence-point loads
      const unsigned long long* src = hcbuf + (size_t)((t - 1) & 1) * DD + lane * 4;
      unsigned long long raw[16];
#pragma unroll
      for (int kb = 0; kb < 4; ++kb) {
#pragma unroll
        for (int q = 0; q < 4; ++q) {
          raw[kb*4+q] = __hip_atomic_load(src + kb * 256 + q,
                                          __ATOMIC_RELAXED, __HIP_MEMORY_SCOPE_AGENT);
        }
      }
#pragma unroll
      for (int kb = 0; kb < 4; ++kb) {
        const int o = kb * 256 + lane * 4;
        const float4 wF = *(const float4*)&lw[o];
        const float4 wI = *(const float4*)&lw[1024 + o];
        const float4 wO = *(const float4*)&lw[2048 + o];
        const float4 wC = *(const float4*)&lw[3072 + o];
        const int b = kb * 4;
#pragma unroll
        for (int q = 0; q < 4; ++q) {
          HC u; u.u = raw[kb*4+q];
          const float hq = u.f.x, cq = u.f.y;
          const float wFq = (q==0)?wF.x:(q==1)?wF.y:(q==2)?wF.z:wF.w;
          const float wIq = (q==0)?wI.x:(q==1)?wI.y:(q==2)?wI.z:wI.w;
          const float wOq = (q==0)?wO.x:(q==1)?wO.y:(q==2)?wO.z:wO.w;
          const float wCq = (q==0)?wC.x:(q==1)?wC.y:(q==2)?wC.z:wC.w;
          aF += wFq * hq;
          aI += wIq * hq;
          aO += wOq * hq;
          aC += wCq * hq + wcc[b+q] * cq;
        }
      }
    }

#pragma unroll
    for (int m = 32; m >= 1; m >>= 1) {
      aF += __shfl_xor(aF, m, 64);
      aI += __shfl_xor(aI, m, 64);
      aO += __shfl_xor(aO, m, 64);
      aC += __shfl_xor(aC, m, 64);
    }

    // biases added exactly once, post-reduction
    const float fg = fast_sigmoid(aF + Bf);
    const float ig = fast_sigmoid(aI + Bi);
    const float og = fast_sigmoid(aO + Bo);
    const float ct = fast_tanh(aC + Bc);
    const float cn = fg * cj + ig * ct;
    const float hn = og * fast_tanh(cn);
    cj = cn;

    if (lane == 0) {
      out[(size_t)t * DD + j] = hn;  // pure output; consumers read hcbuf
      HC u; u.f = make_float2(hn, cn);
      __hip_atomic_store(hcbuf + (size_t)(t & 1) * DD + j, u.u,
                         __ATOMIC_RELAXED, __HIP_MEMORY_SCOPE_AGENT);
    }
    __syncthreads();  // each wave drains vmcnt(0) before s_barrier
    if (threadIdx.x == 0) {
      // release store: safety-net ordering for the hc stores + flag publish
      __hip_atomic_store(&flags[blockIdx.x], (unsigned)(t + 1),
                         __ATOMIC_RELEASE, __HIP_MEMORY_SCOPE_AGENT);
    }
    xc0 = xn0; xc1 = xn1; xc2 = xn2; xc3 = xn3;
  }
}

extern "C" void kernel_launch(void* const* d_in, const int* in_sizes, int n_in,
                              void* d_out, int out_size, void* d_ws, size_t ws_size,
                              hipStream_t stream) {
  const float* X    = (const float*)d_in[0];
  const float* eh   = (const float*)d_in[1];
  const float* ec   = (const float*)d_in[2];
  const float* Wf   = (const float*)d_in[3];
  const float* bf_  = (const float*)d_in[4];
  const float* Wi   = (const float*)d_in[5];
  const float* bi_  = (const float*)d_in[6];
  const float* Wc   = (const float*)d_in[7];
  const float* bc_  = (const float*)d_in[8];
  const float* Wo   = (const float*)d_in[9];
  const float* bo_  = (const float*)d_in[10];
  float* out = (float*)d_out;

  unsigned* flags = (unsigned*)d_ws;                              // 512 B
  unsigned long long* hcbuf = (unsigned long long*)((char*)d_ws + 1024);  // 16 KB

  hipMemsetAsync(d_ws, 0, 1024, stream);

  hipFuncSetAttribute((const void*)lstm_seq,
                      hipFuncAttributeMaxDynamicSharedMemorySize, LDSB);

  void* args[] = {(void*)&X, (void*)&eh, (void*)&ec,
                  (void*)&Wf, (void*)&bf_, (void*)&Wi, (void*)&bi_,
                  (void*)&Wc, (void*)&bc_, (void*)&Wo, (void*)&bo_,
                  (void*)&out, (void*)&hcbuf, (void*)&flags};
  hipError_t e = hipLaunchCooperativeKernel((const void*)lstm_seq,
                                            dim3(NBLK), dim3(NTHR),
                                            args, LDSB, stream);
  if (e != hipSuccess) {
    // plain-launch fallback: 128 blocks x 128KB LDS => 1 block/CU, co-resident
    lstm_seq<<<dim3(NBLK), dim3(NTHR), LDSB, stream>>>(
        X, eh, ec, Wf, bf_, Wi, bi_, Wc, bc_, Wo, bo_, out, hcbuf, flags);
  }
}

// Round 8
// 23266.040 us; speedup vs baseline: 7.4576x; 1.6553x over previous
//
#include <hip/hip_runtime.h>

#define DD 1024        // hidden size
#define TT 8192        // sequence length
#define NBLK 128       // grid blocks == barrier participants
#define NTHR 512       // 8 waves per block
#define RPB 8          // rows per block (one per wave)
#define WLDS (RPB * 4 * DD)        // 32768 floats = 128 KB of weights
#define LDSB (WLDS * 4 + DD * 8)   // + 8 KB hc stage = 136 KB total

__device__ __forceinline__ float fast_sigmoid(float x) {
  x = fminf(fmaxf(x, -30.0f), 30.0f);
  return 1.0f / (1.0f + __expf(-x));
}

__device__ __forceinline__ float fast_tanh(float x) {
  x = fminf(fmaxf(x, -15.0f), 15.0f);
  float e = __expf(2.0f * x);
  return (e - 1.0f) / (e + 1.0f);
}

union HC { unsigned long long u; float2 f; };

// Persistent LSTM. 128KB LDS weights + 8KB LDS hc stage.
// R8 changes vs R7:
//  - wave0 polls flags, then fetches the block's 1024 {h,c} pairs ONCE
//    (16 8B coherence-point loads/lane) and stages them in LDS; waves 1-7
//    read LDS. Coherence-fabric read traffic /8 (was 64KB/block/step).
//  - flag store is RELAXED: __syncthreads drains each wave's vmcnt (hc
//    atomic stores ack'd at the coherence point) before s_barrier, so the
//    post-barrier flag store is ordered without release's buffer_wbl2
//    (R7's WRITE_SIZE=346MB vs 32MB output = wbl2 amplification).
//  - s_sleep(2) poll backoff cuts hot-line contention from 128 spinners.
__global__ __launch_bounds__(NTHR, 2) void lstm_seq(
    const float* __restrict__ X,      // [T, D]
    const float* __restrict__ enc_h,  // [D]
    const float* __restrict__ enc_c,  // [D]
    const float* __restrict__ Wf, const float* __restrict__ bf_,
    const float* __restrict__ Wi, const float* __restrict__ bi_,
    const float* __restrict__ Wc, const float* __restrict__ bc_,
    const float* __restrict__ Wo, const float* __restrict__ bo_,
    float* __restrict__ out,          // [T, D] h_t rows
    unsigned long long* __restrict__ hcbuf,  // [2][D] ring of packed {h,c}
    unsigned* __restrict__ flags)     // [NBLK] packed (512 B)
{
  extern __shared__ float lds[];      // [RPB][4][1024] weights | [1024] float2 hc
  const int wv   = threadIdx.x >> 6;  // wave = local row 0..7
  const int lane = threadIdx.x & 63;
  const int j    = blockIdx.x * RPB + wv;

  // ---- stage h-part weights into LDS (once); gate order f,i,o,C ----
  for (int idx = threadIdx.x; idx < RPB * 4 * 256; idx += NTHR) {
    const int r = idx >> 10, g = (idx >> 8) & 3, q = idx & 255;
    const int row = blockIdx.x * RPB + r;
    const float* ws = (g == 0) ? Wf : (g == 1) ? Wi : (g == 2) ? Wo : Wc;
    *(float4*)&lds[idx * 4] = *(const float4*)(ws + (size_t)row * 2048 + q * 4);
  }

  // ---- per-lane constant weights in registers (x-parts + c-part) ----
  float wxf[16], wxi[16], wxo[16], wcc[16];
#pragma unroll
  for (int kb = 0; kb < 4; ++kb) {
    const int k = 1024 + kb * 256 + lane * 4;
    *(float4*)&wxf[kb*4] = *(const float4*)(Wf + (size_t)j * 2048 + k);
    *(float4*)&wxi[kb*4] = *(const float4*)(Wi + (size_t)j * 2048 + k);
    *(float4*)&wxo[kb*4] = *(const float4*)(Wo + (size_t)j * 2048 + k);
    *(float4*)&wcc[kb*4] = *(const float4*)(Wc + (size_t)j * 2048 + k);
  }
  const float Bf = bf_[j], Bi = bi_[j], Bc = bc_[j], Bo = bo_[j];
  const float* lw = lds + wv * 4096;          // this wave's [4][1024] h-weights
  float2* hst = (float2*)(lds + WLDS);        // [1024] staged {h,c}

  float cj = enc_c[j];  // register carry of this row's cell state

  __syncthreads();

  // x_0 preload; thereafter x_{t+1} is prefetched a full step ahead
  float4 xc0, xc1, xc2, xc3;
  {
    const float* xq = X + lane * 4;
    xc0 = *(const float4*)(xq);       xc1 = *(const float4*)(xq + 256);
    xc2 = *(const float4*)(xq + 512); xc3 = *(const float4*)(xq + 768);
  }

  for (int t = 0; t < TT; ++t) {
    // issue next-step x loads (HBM latency hides under this whole step)
    float4 xn0, xn1, xn2, xn3;
    {
      const size_t tn = (t + 1 < TT) ? (size_t)(t + 1) : (size_t)t;
      const float* xq = X + tn * DD + lane * 4;
      xn0 = *(const float4*)(xq);       xn1 = *(const float4*)(xq + 256);
      xn2 = *(const float4*)(xq + 512); xn3 = *(const float4*)(xq + 768);
    }

    // x-part MACs (barrier-independent; biases added post-reduce — R3 lesson)
    float aF = 0.0f, aI = 0.0f, aO = 0.0f, aC = 0.0f;
#pragma unroll
    for (int kb = 0; kb < 4; ++kb) {
      const float4 xv = (kb==0)?xc0:(kb==1)?xc1:(kb==2)?xc2:xc3;
      const int b = kb * 4;
      aF += wxf[b]*xv.x + wxf[b+1]*xv.y + wxf[b+2]*xv.z + wxf[b+3]*xv.w;
      aI += wxi[b]*xv.x + wxi[b+1]*xv.y + wxi[b+2]*xv.z + wxi[b+3]*xv.w;
      aO += wxo[b]*xv.x + wxo[b+1]*xv.y + wxo[b+2]*xv.z + wxo[b+3]*xv.w;
    }

    if (t > 0) {
      if (threadIdx.x < 64) {  // wave 0: poll, then fetch + stage hc
        const unsigned tt = (unsigned)t;
        for (;;) {
          unsigned a = __hip_atomic_load(&flags[lane     ], __ATOMIC_RELAXED, __HIP_MEMORY_SCOPE_AGENT);
          unsigned b = __hip_atomic_load(&flags[lane + 64], __ATOMIC_RELAXED, __HIP_MEMORY_SCOPE_AGENT);
          if (__all((a >= tt) & (b >= tt))) break;
          __builtin_amdgcn_s_sleep(2);
        }
        // fetch the block's 1024 {h,c} pairs once: 16x 8B coherence loads
        const unsigned long long* src =
            hcbuf + (size_t)((t - 1) & 1) * DD + lane * 4;
        unsigned long long raw[16];
#pragma unroll
        for (int kb = 0; kb < 4; ++kb) {
#pragma unroll
          for (int q = 0; q < 4; ++q) {
            raw[kb*4+q] = __hip_atomic_load(src + kb * 256 + q,
                                            __ATOMIC_RELAXED, __HIP_MEMORY_SCOPE_AGENT);
          }
        }
#pragma unroll
        for (int kb = 0; kb < 4; ++kb) {
#pragma unroll
          for (int q = 0; q < 4; ++q) {
            HC u; u.u = raw[kb*4+q];
            hst[kb * 256 + lane * 4 + q] = u.f;
          }
        }
      }
      __syncthreads();  // stage visible to all 8 waves
    }

    if (t == 0) {
      const float* hp = enc_h + lane * 4;
      const float* cp = enc_c + lane * 4;
#pragma unroll
      for (int kb = 0; kb < 4; ++kb) {
        const int o = kb * 256 + lane * 4;
        const float4 hv = *(const float4*)(hp + kb * 256);
        const float4 cc = *(const float4*)(cp + kb * 256);
        const float4 wF = *(const float4*)&lw[o];
        const float4 wI = *(const float4*)&lw[1024 + o];
        const float4 wO = *(const float4*)&lw[2048 + o];
        const float4 wC = *(const float4*)&lw[3072 + o];
        const int b = kb * 4;
        aF += wF.x*hv.x + wF.y*hv.y + wF.z*hv.z + wF.w*hv.w;
        aI += wI.x*hv.x + wI.y*hv.y + wI.z*hv.z + wI.w*hv.w;
        aO += wO.x*hv.x + wO.y*hv.y + wO.z*hv.z + wO.w*hv.w;
        aC += wC.x*hv.x + wC.y*hv.y + wC.z*hv.z + wC.w*hv.w;
        aC += wcc[b]*cc.x + wcc[b+1]*cc.y + wcc[b+2]*cc.z + wcc[b+3]*cc.w;
      }
    } else {
      // MACs sourced from the LDS stage: {h,c} interleaved as float2
#pragma unroll
      for (int kb = 0; kb < 4; ++kb) {
        const int col = kb * 256 + lane * 4;
        const int o   = kb * 256 + lane * 4;
        const float4 p0 = *(const float4*)&hst[col];      // h0,c0,h1,c1
        const float4 p1 = *(const float4*)&hst[col + 2];  // h2,c2,h3,c3
        const float4 wF = *(const float4*)&lw[o];
        const float4 wI = *(const float4*)&lw[1024 + o];
        const float4 wO = *(const float4*)&lw[2048 + o];
        const float4 wC = *(const float4*)&lw[3072 + o];
        const int b = kb * 4;
        aF += wF.x*p0.x + wF.y*p0.z + wF.z*p1.x + wF.w*p1.z;
        aI += wI.x*p0.x + wI.y*p0.z + wI.z*p1.x + wI.w*p1.z;
        aO += wO.x*p0.x + wO.y*p0.z + wO.z*p1.x + wO.w*p1.z;
        aC += wC.x*p0.x + wC.y*p0.z + wC.z*p1.x + wC.w*p1.z;
        aC += wcc[b]*p0.y + wcc[b+1]*p0.w + wcc[b+2]*p1.y + wcc[b+3]*p1.w;
      }
    }

#pragma unroll
    for (int m = 32; m >= 1; m >>= 1) {
      aF += __shfl_xor(aF, m, 64);
      aI += __shfl_xor(aI, m, 64);
      aO += __shfl_xor(aO, m, 64);
      aC += __shfl_xor(aC, m, 64);
    }

    // biases added exactly once, post-reduction
    const float fg = fast_sigmoid(aF + Bf);
    const float ig = fast_sigmoid(aI + Bi);
    const float og = fast_sigmoid(aO + Bo);
    const float ct = fast_tanh(aC + Bc);
    const float cn = fg * cj + ig * ct;
    const float hn = og * fast_tanh(cn);
    cj = cn;

    if (lane == 0) {
      out[(size_t)t * DD + j] = hn;  // plain store; host reads after kernel end
      HC u; u.f = make_float2(hn, cn);
      __hip_atomic_store(hcbuf + (size_t)(t & 1) * DD + j, u.u,
                         __ATOMIC_RELAXED, __HIP_MEMORY_SCOPE_AGENT);
    }
    __syncthreads();  // each wave drains vmcnt(0): hc stores ack'd at IF$
    if (threadIdx.x == 0) {
      // relaxed: ordering provided by the per-wave vmcnt drain above
      __hip_atomic_store(&flags[blockIdx.x], (unsigned)(t + 1),
                         __ATOMIC_RELAXED, __HIP_MEMORY_SCOPE_AGENT);
    }
    xc0 = xn0; xc1 = xn1; xc2 = xn2; xc3 = xn3;
  }
}

extern "C" void kernel_launch(void* const* d_in, const int* in_sizes, int n_in,
                              void* d_out, int out_size, void* d_ws, size_t ws_size,
                              hipStream_t stream) {
  const float* X    = (const float*)d_in[0];
  const float* eh   = (const float*)d_in[1];
  const float* ec   = (const float*)d_in[2];
  const float* Wf   = (const float*)d_in[3];
  const float* bf_  = (const float*)d_in[4];
  const float* Wi   = (const float*)d_in[5];
  const float* bi_  = (const float*)d_in[6];
  const float* Wc   = (const float*)d_in[7];
  const float* bc_  = (const float*)d_in[8];
  const float* Wo   = (const float*)d_in[9];
  const float* bo_  = (const float*)d_in[10];
  float* out = (float*)d_out;

  unsigned* flags = (unsigned*)d_ws;                              // 512 B
  unsigned long long* hcbuf = (unsigned long long*)((char*)d_ws + 1024);  // 16 KB

  hipMemsetAsync(d_ws, 0, 1024, stream);

  hipFuncSetAttribute((const void*)lstm_seq,
                      hipFuncAttributeMaxDynamicSharedMemorySize, LDSB);

  void* args[] = {(void*)&X, (void*)&eh, (void*)&ec,
                  (void*)&Wf, (void*)&bf_, (void*)&Wi, (void*)&bi_,
                  (void*)&Wc, (void*)&bc_, (void*)&Wo, (void*)&bo_,
                  (void*)&out, (void*)&hcbuf, (void*)&flags};
  hipError_t e = hipLaunchCooperativeKernel((const void*)lstm_seq,
                                            dim3(NBLK), dim3(NTHR),
                                            args, LDSB, stream);
  if (e != hipSuccess) {
    // plain-launch fallback: 128 blocks x 136KB LDS => 1 block/CU, co-resident
    lstm_seq<<<dim3(NBLK), dim3(NTHR), LDSB, stream>>>(
        X, eh, ec, Wf, bf_, Wi, bi_, Wc, bc_, Wo, bo_, out, hcbuf, flags);
  }
}